// Round 24
// baseline (54.057 us; speedup 1.0000x reference)
//
#include <hip/hip_runtime.h>

#define B_ 4
#define N_ 384
#define D_ 64
#define H_ 64
#define BN_ (B_ * N_)   // 1536
#define ROW_ (N_ * H_)  // 24576 floats per batch of PA/PC
#define NTP_ 12         // 32-row j-tile-pairs per batch
#define LDW_ 68         // padded LDS row stride in words (64+4: 2-way max)

typedef float f32x4 __attribute__((ext_vector_type(4)));
typedef _Float16 half8 __attribute__((ext_vector_type(8)));
typedef __fp16 fp16x2 __attribute__((ext_vector_type(2)));   // cvt_pkrtz result type

union frag_cast { f32x4 f; half8 h; };

// ---------------------------------------------------------------------------
// Kernel A (r18-proj): projections, 4 rows per block (blocks 0..383);
// w2prep in blocks 384..391. Bit-exact per-output fmaf chains.
// ---------------------------------------------------------------------------
__global__ __launch_bounds__(256) void proj_kernel(
    const float* __restrict__ X, const float* __restrict__ Y,
    const float* __restrict__ Wxx1, const float* __restrict__ bxx1,
    const float* __restrict__ Wyx1, const float* __restrict__ byx1,
    const float* __restrict__ W2xx, const float* __restrict__ W2yx,
    float* __restrict__ PAxx, float* __restrict__ PCxx,
    float* __restrict__ PAyx, float* __restrict__ PCyx,
    _Float16* __restrict__ W2F)
{
    if (blockIdx.x >= 384) {
        int t = (blockIdx.x - 384) * 256 + threadIdx.x;   // 2048 frag-lanes
        int br = t >> 10;
        int q  = (t >> 6) & 15;
        int l  = t & 63;
        int nt = q >> 2, kt = (q >> 1) & 1, part = q & 1;
        const float* W2 = br ? W2yx : W2xx;
        int n = nt * 16 + (l & 15);
        int g = l >> 4;
        _Float16* dst = W2F + t * 8;
#pragma unroll
        for (int e = 0; e < 8; ++e) {
            int h = kt * 32 + g * 8 + e;
            float v = W2[h * 64 + n];
            _Float16 hi = (_Float16)v;
            _Float16 lo = (_Float16)(v - (float)hi);
            dst[e] = part ? lo : hi;
        }
        return;
    }

    int blk = blockIdx.x;            // rows blk*4 .. blk*4+3 (never straddle b)
    int t = threadIdx.x;
    int which = t >> 6, h = t & 63;

    __shared__ float xr[4][64];
    __shared__ float yr[4][64];
    xr[t >> 6][t & 63] = X[(blk * 4 + (t >> 6)) * 64 + (t & 63)];
    yr[t >> 6][t & 63] = Y[(blk * 4 + (t >> 6)) * 64 + (t & 63)];
    __syncthreads();

    const float (*v)[64] = (which == 2) ? yr : xr;
    const float* W = (which < 2) ? Wxx1 : Wyx1;
    int rowoff = (which & 1) ? 64 : 0;

    float acc[4];
    float binit = 0.f;
    if (which == 1) binit = bxx1[h];
    if (which == 3) binit = byx1[h];
#pragma unroll
    for (int r = 0; r < 4; ++r) acc[r] = binit;

#pragma unroll
    for (int d = 0; d < 64; ++d) {
        float wv = W[(rowoff + d) * 64 + h];
#pragma unroll
        for (int r = 0; r < 4; ++r)
            acc[r] = fmaf(v[r][d], wv, acc[r]);
    }

    float* dst = (which == 0) ? PAxx : (which == 1) ? PCxx
               : (which == 2) ? PAyx : PCyx;
#pragma unroll
    for (int r = 0; r < 4; ++r)
        dst[(blk * 4 + r) * 64 + h] = acc[r];
}

// ---------------------------------------------------------------------------
// Kernel B (r24): r17 per-wave body, 2-WAVE blocks (128 thr, 2 i's/block).
// grid = 1536 = br x 768 i-pairs. 12 waves/CU reg-cap -> 6 independent
// blocks/CU (vs r17's 3): tests whether barrier-desync stream count is the
// latency-filling limiter. One i per wave (r8/r18 invariant). LDS tile
// shared by the block's 2 waves; 32 j-rows per phase; 2-buffer ring.
//   zsum[br][ig][k] = sum_{w=0,1} max_j relu(PA[b,j,:]+PC[ig*2+w,:]).W2[:,k]
// split-f16 MFMA (hi*hi + hi*lo + lo*hi), fp32-grade.
// NOTE r14/r15: no last-block fusion. r8/r18: one i per wave.
// ---------------------------------------------------------------------------
__global__ __launch_bounds__(128, 3) void pair_mfma_kernel(
    const float* __restrict__ PAxx, const float* __restrict__ PCxx,
    const float* __restrict__ PAyx, const float* __restrict__ PCyx,
    const f32x4* __restrict__ W2F,
    float* __restrict__ zxxs, float* __restrict__ zyxs)
{
    // XCD-chunked swizzle (bijective: 1536 = 8 * 192)
    int bid = blockIdx.x;
    int blk = (bid & 7) * 192 + (bid >> 3);
    int br = blk / 768;
    int ig = blk % 768;              // i-pair: bi = ig*2 + w (never straddles b)
    int t = threadIdx.x;             // 0..127
    int w = t >> 6, l = t & 63;
    int g = l >> 4, m = l & 15;
    int bi = ig * 2 + w;
    int b  = bi / N_;

    const float* PA = br ? PAyx : PAxx;
    const float* PC = br ? PCyx : PCxx;

    __shared__ float lbuf[2][32 * LDW_];   // 2 x 8.7 KB
    __shared__ float zsums[2][64];         // epilogue i-sum buffer

    // B fragments (all 64 k): bf[nt][kt][part], 16 x half8 = 64 regs.
    // Opaque pin: value comes out of asm -> rematerialization impossible.
    half8 bf[4][2][2];
    const f32x4* Wb = W2F + br * 1024;
#pragma unroll
    for (int q = 0; q < 16; ++q) {
        frag_cast u;
        u.f = Wb[q * 64 + l];
        asm volatile("" : "+v"(u.f));
        bf[q >> 2][(q >> 1) & 1][q & 1] = u.h;
    }

    // pc values this lane needs: h = kt*32 + g*8 + {0..7}
    f32x4 pcq[4];
#pragma unroll
    for (int kt = 0; kt < 2; ++kt) {
        pcq[kt * 2 + 0] = *(const f32x4*)(PC + bi * 64 + kt * 32 + g * 8);
        pcq[kt * 2 + 1] = *(const f32x4*)(PC + bi * 64 + kt * 32 + g * 8 + 4);
    }

    float mm[4] = {-3.0e38f, -3.0e38f, -3.0e38f, -3.0e38f};

    // staging: 128 threads x 4 slots per 32-row tile-pair (512 slots of 4B x4)
    // slot s = q*128 + t: row = s>>4, grp = s&15
    int goff[4], loff[4];
#pragma unroll
    for (int q = 0; q < 4; ++q) {
        int s = q * 128 + t;
        goff[q] = (s >> 4) * 64 + (s & 15) * 4;
        loff[q] = (s >> 4) * LDW_ + (s & 15) * 4;
    }
    const float* gbase = PA + b * ROW_;    // + pt*2048 + goff[q]

    // prologue: stage tile-pair 0 into buf 0
#pragma unroll
    for (int q = 0; q < 4; ++q)
        *(f32x4*)(&lbuf[0][0] + loff[q]) = *(const f32x4*)(gbase + goff[q]);
    __syncthreads();

    const f32x4 vzero = {0.f, 0.f, 0.f, 0.f};
    int cur = 0;

#pragma unroll 1
    for (int pt = 0; pt < NTP_; ++pt) {
        // issue next tile-pair's loads early (hide under this phase's compute)
        f32x4 gn[4];
        if (pt + 1 < NTP_) {
#pragma unroll
            for (int q = 0; q < 4; ++q)
                gn[q] = *(const f32x4*)(gbase + (pt + 1) * 2048 + goff[q]);
        }

        // two 16-row subtiles, sequential (ah/al registers reused)
#pragma unroll
        for (int st = 0; st < 2; ++st) {
            const float* lrd = &lbuf[0][0] + cur * (32 * LDW_)
                             + (st * 16 + m) * LDW_ + g * 8;
            f32x4 s0 = *(const f32x4*)(lrd);
            f32x4 s1 = *(const f32x4*)(lrd + 4);
            f32x4 s2 = *(const f32x4*)(lrd + 32);
            f32x4 s3 = *(const f32x4*)(lrd + 36);

            // A-prep: x = relu(pa + pc); split x = hi + lo (pkrtz).
            half8 ah[2], al[2];
#pragma unroll
            for (int kt = 0; kt < 2; ++kt) {
                f32x4 xa = (kt ? s2 : s0) + pcq[kt * 2 + 0];
                f32x4 xb = (kt ? s3 : s1) + pcq[kt * 2 + 1];
                xa = __builtin_elementwise_max(xa, vzero);
                xb = __builtin_elementwise_max(xb, vzero);
                fp16x2* ahp = (fp16x2*)&ah[kt];
                fp16x2* alp = (fp16x2*)&al[kt];
#pragma unroll
                for (int p2 = 0; p2 < 2; ++p2) {
                    fp16x2 hpa = __builtin_amdgcn_cvt_pkrtz(xa[p2 * 2], xa[p2 * 2 + 1]);
                    fp16x2 hpb = __builtin_amdgcn_cvt_pkrtz(xb[p2 * 2], xb[p2 * 2 + 1]);
                    ahp[p2]     = hpa;
                    ahp[p2 + 2] = hpb;
                    alp[p2]     = __builtin_amdgcn_cvt_pkrtz(xa[p2 * 2]     - (float)hpa[0],
                                                             xa[p2 * 2 + 1] - (float)hpa[1]);
                    alp[p2 + 2] = __builtin_amdgcn_cvt_pkrtz(xb[p2 * 2]     - (float)hpb[0],
                                                             xb[p2 * 2 + 1] - (float)hpb[1]);
                }
            }

            // 4 independent accumulator chains (one per nt), depth 6
#pragma unroll
            for (int nt = 0; nt < 4; ++nt) {
                f32x4 a = {0.f, 0.f, 0.f, 0.f};
#pragma unroll
                for (int kt = 0; kt < 2; ++kt) {
                    a = __builtin_amdgcn_mfma_f32_16x16x32_f16(ah[kt], bf[nt][kt][0], a, 0, 0, 0);
                    a = __builtin_amdgcn_mfma_f32_16x16x32_f16(ah[kt], bf[nt][kt][1], a, 0, 0, 0);
                    a = __builtin_amdgcn_mfma_f32_16x16x32_f16(al[kt], bf[nt][kt][0], a, 0, 0, 0);
                }
                mm[nt] = fmaxf(mm[nt],
                               fmaxf(fmaxf(a[0], a[1]), fmaxf(a[2], a[3])));
            }
        }

        // write next tile-pair into the other buffer; one barrier per phase
        if (pt + 1 < NTP_) {
#pragma unroll
            for (int q = 0; q < 4; ++q)
                *(f32x4*)(&lbuf[0][0] + (cur ^ 1) * (32 * LDW_) + loff[q]) = gn[q];
        }
        __syncthreads();
        cur ^= 1;
    }

    // reduce across the 4 row groups; then every lane holds all 4 nt maxima
#pragma unroll
    for (int nt = 0; nt < 4; ++nt) {
        float v = mm[nt];
        v = fmaxf(v, __shfl_xor(v, 16));
        v = fmaxf(v, __shfl_xor(v, 32));
        mm[nt] = v;
    }
    // lane l owns output column k=l: select mm[l>>4]
    float z = (l < 32) ? ((l < 16) ? mm[0] : mm[1])
                       : ((l < 48) ? mm[2] : mm[3]);

    // block-level sum over the 2 i's (one per wave), deterministic order
    zsums[w][l] = z;
    __syncthreads();
    if (w == 0) {
        float s = zsums[0][l] + zsums[1][l];
        (br ? zyxs : zxxs)[ig * 64 + l] = s;
    }
}

// ---------------------------------------------------------------------------
// Kernel C: Z_X from 192 partials per batch; decoder.
// ---------------------------------------------------------------------------
__global__ __launch_bounds__(256) void head_kernel(
    const float* __restrict__ zxxs, const float* __restrict__ zyxs,
    const float* __restrict__ b2xx, const float* __restrict__ b2yx,
    const float* __restrict__ Wd1, const float* __restrict__ bd1,
    const float* __restrict__ Wd2, const float* __restrict__ bd2,
    float* __restrict__ out)
{
    int b = blockIdx.x;
    int t = threadIdx.x;
    int ig = t >> 6, h = t & 63;

    __shared__ float sbuf[4][64];
    __shared__ float zx[64];

    float s = 0.f;
    for (int q = ig; q < 192; q += 4) {
        int idx = (b * 192 + q) * 64 + h;
        s += zxxs[idx] - zyxs[idx];
    }
    sbuf[ig][h] = s;
    __syncthreads();
    if (t < 64)
        zx[t] = sbuf[0][t] + sbuf[1][t] + sbuf[2][t] + sbuf[3][t]
              + (float)N_ * (b2xx[t] - b2yx[t]);
    __syncthreads();

    if (t < 64) {
        float acc = bd1[t];
#pragma unroll
        for (int d = 0; d < 64; ++d)
            acc = fmaf(zx[d], Wd1[d * 64 + t] + Wd1[(64 + d) * 64 + t], acc);
        float h1 = fmaxf(acc, 0.f);
        float r = h1 * Wd2[t];
#pragma unroll
        for (int off = 32; off; off >>= 1) r += __shfl_down(r, off);
        if (t == 0) out[b] = r + bd2[0];
    }
}

extern "C" void kernel_launch(void* const* d_in, const int* in_sizes, int n_in,
                              void* d_out, int out_size, void* d_ws, size_t ws_size,
                              hipStream_t stream) {
    const float* X    = (const float*)d_in[0];
    const float* Y    = (const float*)d_in[1];
    const float* Wxx1 = (const float*)d_in[2];
    const float* bxx1 = (const float*)d_in[3];
    const float* W2xx = (const float*)d_in[4];
    const float* b2xx = (const float*)d_in[5];
    // d_in[6..9]  = xy branch (dead code)
    const float* Wyx1 = (const float*)d_in[10];
    const float* byx1 = (const float*)d_in[11];
    const float* W2yx = (const float*)d_in[12];
    const float* b2yx = (const float*)d_in[13];
    // d_in[14..17] = yy branch (dead code)
    const float* Wd1  = (const float*)d_in[18];
    const float* bd1  = (const float*)d_in[19];
    const float* Wd2  = (const float*)d_in[20];
    const float* bd2  = (const float*)d_in[21];

    float* ws   = (float*)d_ws;
    float* PAxx = ws;
    float* PCxx = ws + 1 * (BN_ * H_);
    float* PAyx = ws + 2 * (BN_ * H_);
    float* PCyx = ws + 3 * (BN_ * H_);
    float* zxxs = ws + 4 * (BN_ * H_);                 // 768*64 floats
    float* zyxs = ws + 4 * (BN_ * H_) + 768 * 64;      // 768*64 floats
    _Float16* W2F = (_Float16*)(ws + 5 * (BN_ * H_));  // 32 KiB, 16B-aligned

    proj_kernel<<<384 + 8, 256, 0, stream>>>(X, Y, Wxx1, bxx1, Wyx1, byx1,
                                             W2xx, W2yx,
                                             PAxx, PCxx, PAyx, PCyx, W2F);
    pair_mfma_kernel<<<1536, 128, 0, stream>>>(PAxx, PCxx, PAyx, PCyx,
                                               (const f32x4*)W2F, zxxs, zyxs);
    head_kernel<<<B_, 256, 0, stream>>>(zxxs, zyxs, b2xx, b2yx,
                                        Wd1, bd1, Wd2, bd2, (float*)d_out);
}

// Round 25
// 47.328 us; speedup vs baseline: 1.1422x; 1.1422x over previous
//
#include <hip/hip_runtime.h>

#define B_ 4
#define N_ 384
#define D_ 64
#define H_ 64
#define BN_ (B_ * N_)   // 1536
#define ROW_ (N_ * H_)  // 24576 floats per batch of PA/PC
#define NTP_ 12         // 32-row j-tile-pairs per batch
#define LDW_ 68         // padded LDS row stride in words (64+4: 2-way max)

typedef float f32x4 __attribute__((ext_vector_type(4)));
typedef _Float16 half8 __attribute__((ext_vector_type(8)));
typedef __fp16 fp16x2 __attribute__((ext_vector_type(2)));   // cvt_pkrtz result type

union frag_cast { f32x4 f; half8 h; };

// ---------------------------------------------------------------------------
// Kernel A (r18-proj): projections, 4 rows per block (blocks 0..383);
// w2prep in blocks 384..391. Bit-exact per-output fmaf chains.
// ---------------------------------------------------------------------------
__global__ __launch_bounds__(256) void proj_kernel(
    const float* __restrict__ X, const float* __restrict__ Y,
    const float* __restrict__ Wxx1, const float* __restrict__ bxx1,
    const float* __restrict__ Wyx1, const float* __restrict__ byx1,
    const float* __restrict__ W2xx, const float* __restrict__ W2yx,
    float* __restrict__ PAxx, float* __restrict__ PCxx,
    float* __restrict__ PAyx, float* __restrict__ PCyx,
    _Float16* __restrict__ W2F)
{
    if (blockIdx.x >= 384) {
        int t = (blockIdx.x - 384) * 256 + threadIdx.x;   // 2048 frag-lanes
        int br = t >> 10;
        int q  = (t >> 6) & 15;
        int l  = t & 63;
        int nt = q >> 2, kt = (q >> 1) & 1, part = q & 1;
        const float* W2 = br ? W2yx : W2xx;
        int n = nt * 16 + (l & 15);
        int g = l >> 4;
        _Float16* dst = W2F + t * 8;
#pragma unroll
        for (int e = 0; e < 8; ++e) {
            int h = kt * 32 + g * 8 + e;
            float v = W2[h * 64 + n];
            _Float16 hi = (_Float16)v;
            _Float16 lo = (_Float16)(v - (float)hi);
            dst[e] = part ? lo : hi;
        }
        return;
    }

    int blk = blockIdx.x;            // rows blk*4 .. blk*4+3 (never straddle b)
    int t = threadIdx.x;
    int which = t >> 6, h = t & 63;

    __shared__ float xr[4][64];
    __shared__ float yr[4][64];
    xr[t >> 6][t & 63] = X[(blk * 4 + (t >> 6)) * 64 + (t & 63)];
    yr[t >> 6][t & 63] = Y[(blk * 4 + (t >> 6)) * 64 + (t & 63)];
    __syncthreads();

    const float (*v)[64] = (which == 2) ? yr : xr;
    const float* W = (which < 2) ? Wxx1 : Wyx1;
    int rowoff = (which & 1) ? 64 : 0;

    float acc[4];
    float binit = 0.f;
    if (which == 1) binit = bxx1[h];
    if (which == 3) binit = byx1[h];
#pragma unroll
    for (int r = 0; r < 4; ++r) acc[r] = binit;

#pragma unroll
    for (int d = 0; d < 64; ++d) {
        float wv = W[(rowoff + d) * 64 + h];
#pragma unroll
        for (int r = 0; r < 4; ++r)
            acc[r] = fmaf(v[r][d], wv, acc[r]);
    }

    float* dst = (which == 0) ? PAxx : (which == 1) ? PCxx
               : (which == 2) ? PAyx : PCyx;
#pragma unroll
    for (int r = 0; r < 4; ++r)
        dst[(blk * 4 + r) * 64 + h] = acc[r];
}

// ---------------------------------------------------------------------------
// Kernel B (r17 verified body — session best, 47.4 us, absmax 0.0).
// 768 blocks x 256 thr; block = (br, 4 consecutive bi); wave w owns
// bi = ig*4 + w over ALL 384 j; 4 waves share staged PA tiles via LDS;
// 32 j-rows per barrier phase; 2-buffer ring; epilogue sums the 4 i's.
//   zsum[br][ig][k] = sum_w max_j relu(PA[b,j,:]+PC[ig*4+w,:]).W2[:,k]
// split-f16 MFMA (hi*hi + hi*lo + lo*hi), fp32-grade.
// Session A/B ledger (all neutral on this structure): pipeline depth (r12),
// barrier cadence (r13), occupancy shaping (r10), block shape (r6/r18/r24),
// setprio (r20), global_load_lds (r21), MFMA 32x32 shape (r22).
// Negative: last-block fusion (r14/r15: device fences cost 100-280 us);
// 2-i-per-wave (r8/r18: register spill); 2-wave blocks (r24: 2x staging).
// ---------------------------------------------------------------------------
__global__ __launch_bounds__(256, 3) void pair_mfma_kernel(
    const float* __restrict__ PAxx, const float* __restrict__ PCxx,
    const float* __restrict__ PAyx, const float* __restrict__ PCyx,
    const f32x4* __restrict__ W2F,
    float* __restrict__ zxxs, float* __restrict__ zyxs)
{
    // XCD-chunked swizzle (bijective: 768 = 8 * 96)
    int bid = blockIdx.x;
    int blk = (bid & 7) * 96 + (bid >> 3);
    int br = blk / 384;
    int ig = blk % 384;              // i-group: bi = ig*4 + w (never straddles b)
    int t = threadIdx.x;
    int w = t >> 6, l = t & 63;
    int g = l >> 4, m = l & 15;
    int bi = ig * 4 + w;
    int b  = bi / N_;

    const float* PA = br ? PAyx : PAxx;
    const float* PC = br ? PCyx : PCxx;

    __shared__ float lbuf[2][32 * LDW_];   // 2 x 8.7 KB
    __shared__ float zsums[4][64];         // epilogue i-sum buffer

    // B fragments (all 64 k): bf[nt][kt][part], 16 x half8 = 64 regs.
    // Opaque pin: value comes out of asm -> rematerialization impossible.
    half8 bf[4][2][2];
    const f32x4* Wb = W2F + br * 1024;
#pragma unroll
    for (int q = 0; q < 16; ++q) {
        frag_cast u;
        u.f = Wb[q * 64 + l];
        asm volatile("" : "+v"(u.f));
        bf[q >> 2][(q >> 1) & 1][q & 1] = u.h;
    }

    // pc values this lane needs: h = kt*32 + g*8 + {0..7}
    f32x4 pcq[4];
#pragma unroll
    for (int kt = 0; kt < 2; ++kt) {
        pcq[kt * 2 + 0] = *(const f32x4*)(PC + bi * 64 + kt * 32 + g * 8);
        pcq[kt * 2 + 1] = *(const f32x4*)(PC + bi * 64 + kt * 32 + g * 8 + 4);
    }

    float mm[4] = {-3.0e38f, -3.0e38f, -3.0e38f, -3.0e38f};

    // staging: thread t stages rows srow and srow+16, 4-float group scg
    int srow = t >> 4;               // 0..15
    int scg  = t & 15;               // 0..15
    const float* gsrc = PA + b * ROW_ + srow * 64 + scg * 4;  // + pt*2048
    int soff = srow * LDW_ + scg * 4;

    // prologue: stage tile-pair 0 into buf 0
    *(f32x4*)(&lbuf[0][0] + soff) = *(const f32x4*)(gsrc);
    *(f32x4*)(&lbuf[0][0] + soff + 16 * LDW_) = *(const f32x4*)(gsrc + 1024);
    __syncthreads();

    const f32x4 vzero = {0.f, 0.f, 0.f, 0.f};
    int cur = 0;

#pragma unroll 1
    for (int pt = 0; pt < NTP_; ++pt) {
        // issue next tile-pair's loads early (hide under this phase's compute)
        f32x4 gn0, gn1;
        if (pt + 1 < NTP_) {
            gn0 = *(const f32x4*)(gsrc + (pt + 1) * 2048);
            gn1 = *(const f32x4*)(gsrc + (pt + 1) * 2048 + 1024);
        }

        // two 16-row subtiles, sequential (ah/al registers reused)
#pragma unroll
        for (int st = 0; st < 2; ++st) {
            const float* lrd = &lbuf[0][0] + cur * (32 * LDW_)
                             + (st * 16 + m) * LDW_ + g * 8;
            f32x4 s0 = *(const f32x4*)(lrd);
            f32x4 s1 = *(const f32x4*)(lrd + 4);
            f32x4 s2 = *(const f32x4*)(lrd + 32);
            f32x4 s3 = *(const f32x4*)(lrd + 36);

            // A-prep: x = relu(pa + pc); split x = hi + lo (pkrtz).
            half8 ah[2], al[2];
#pragma unroll
            for (int kt = 0; kt < 2; ++kt) {
                f32x4 xa = (kt ? s2 : s0) + pcq[kt * 2 + 0];
                f32x4 xb = (kt ? s3 : s1) + pcq[kt * 2 + 1];
                xa = __builtin_elementwise_max(xa, vzero);
                xb = __builtin_elementwise_max(xb, vzero);
                fp16x2* ahp = (fp16x2*)&ah[kt];
                fp16x2* alp = (fp16x2*)&al[kt];
#pragma unroll
                for (int p2 = 0; p2 < 2; ++p2) {
                    fp16x2 hpa = __builtin_amdgcn_cvt_pkrtz(xa[p2 * 2], xa[p2 * 2 + 1]);
                    fp16x2 hpb = __builtin_amdgcn_cvt_pkrtz(xb[p2 * 2], xb[p2 * 2 + 1]);
                    ahp[p2]     = hpa;
                    ahp[p2 + 2] = hpb;
                    alp[p2]     = __builtin_amdgcn_cvt_pkrtz(xa[p2 * 2]     - (float)hpa[0],
                                                             xa[p2 * 2 + 1] - (float)hpa[1]);
                    alp[p2 + 2] = __builtin_amdgcn_cvt_pkrtz(xb[p2 * 2]     - (float)hpb[0],
                                                             xb[p2 * 2 + 1] - (float)hpb[1]);
                }
            }

            // 4 independent accumulator chains (one per nt), depth 6
#pragma unroll
            for (int nt = 0; nt < 4; ++nt) {
                f32x4 a = {0.f, 0.f, 0.f, 0.f};
#pragma unroll
                for (int kt = 0; kt < 2; ++kt) {
                    a = __builtin_amdgcn_mfma_f32_16x16x32_f16(ah[kt], bf[nt][kt][0], a, 0, 0, 0);
                    a = __builtin_amdgcn_mfma_f32_16x16x32_f16(ah[kt], bf[nt][kt][1], a, 0, 0, 0);
                    a = __builtin_amdgcn_mfma_f32_16x16x32_f16(al[kt], bf[nt][kt][0], a, 0, 0, 0);
                }
                mm[nt] = fmaxf(mm[nt],
                               fmaxf(fmaxf(a[0], a[1]), fmaxf(a[2], a[3])));
            }
        }

        // write next tile-pair into the other buffer; one barrier per phase
        if (pt + 1 < NTP_) {
            *(f32x4*)(&lbuf[0][0] + (cur ^ 1) * (32 * LDW_) + soff) = gn0;
            *(f32x4*)(&lbuf[0][0] + (cur ^ 1) * (32 * LDW_) + soff + 16 * LDW_) = gn1;
        }
        __syncthreads();
        cur ^= 1;
    }

    // reduce across the 4 row groups; then every lane holds all 4 nt maxima
#pragma unroll
    for (int nt = 0; nt < 4; ++nt) {
        float v = mm[nt];
        v = fmaxf(v, __shfl_xor(v, 16));
        v = fmaxf(v, __shfl_xor(v, 32));
        mm[nt] = v;
    }
    // lane l owns output column k=l: select mm[l>>4]
    float z = (l < 32) ? ((l < 16) ? mm[0] : mm[1])
                       : ((l < 48) ? mm[2] : mm[3]);

    // block-level sum over the 4 i's (one per wave), deterministic order
    zsums[w][l] = z;
    __syncthreads();
    if (w == 0) {
        float s = ((zsums[0][l] + zsums[1][l]) + zsums[2][l]) + zsums[3][l];
        (br ? zyxs : zxxs)[ig * 64 + l] = s;
    }
}

// ---------------------------------------------------------------------------
// Kernel C (r17): Z_X from 96 partials per batch; decoder.
// ---------------------------------------------------------------------------
__global__ __launch_bounds__(256) void head_kernel(
    const float* __restrict__ zxxs, const float* __restrict__ zyxs,
    const float* __restrict__ b2xx, const float* __restrict__ b2yx,
    const float* __restrict__ Wd1, const float* __restrict__ bd1,
    const float* __restrict__ Wd2, const float* __restrict__ bd2,
    float* __restrict__ out)
{
    int b = blockIdx.x;
    int t = threadIdx.x;
    int ig = t >> 6, h = t & 63;

    __shared__ float sbuf[4][64];
    __shared__ float zx[64];

    float s = 0.f;
    for (int q = ig; q < 96; q += 4) {
        int idx = (b * 96 + q) * 64 + h;
        s += zxxs[idx] - zyxs[idx];
    }
    sbuf[ig][h] = s;
    __syncthreads();
    if (t < 64)
        zx[t] = sbuf[0][t] + sbuf[1][t] + sbuf[2][t] + sbuf[3][t]
              + (float)N_ * (b2xx[t] - b2yx[t]);
    __syncthreads();

    if (t < 64) {
        float acc = bd1[t];
#pragma unroll
        for (int d = 0; d < 64; ++d)
            acc = fmaf(zx[d], Wd1[d * 64 + t] + Wd1[(64 + d) * 64 + t], acc);
        float h1 = fmaxf(acc, 0.f);
        float r = h1 * Wd2[t];
#pragma unroll
        for (int off = 32; off; off >>= 1) r += __shfl_down(r, off);
        if (t == 0) out[b] = r + bd2[0];
    }
}

extern "C" void kernel_launch(void* const* d_in, const int* in_sizes, int n_in,
                              void* d_out, int out_size, void* d_ws, size_t ws_size,
                              hipStream_t stream) {
    const float* X    = (const float*)d_in[0];
    const float* Y    = (const float*)d_in[1];
    const float* Wxx1 = (const float*)d_in[2];
    const float* bxx1 = (const float*)d_in[3];
    const float* W2xx = (const float*)d_in[4];
    const float* b2xx = (const float*)d_in[5];
    // d_in[6..9]  = xy branch (dead code)
    const float* Wyx1 = (const float*)d_in[10];
    const float* byx1 = (const float*)d_in[11];
    const float* W2yx = (const float*)d_in[12];
    const float* b2yx = (const float*)d_in[13];
    // d_in[14..17] = yy branch (dead code)
    const float* Wd1  = (const float*)d_in[18];
    const float* bd1  = (const float*)d_in[19];
    const float* Wd2  = (const float*)d_in[20];
    const float* bd2  = (const float*)d_in[21];

    float* ws   = (float*)d_ws;
    float* PAxx = ws;
    float* PCxx = ws + 1 * (BN_ * H_);
    float* PAyx = ws + 2 * (BN_ * H_);
    float* PCyx = ws + 3 * (BN_ * H_);
    float* zxxs = ws + 4 * (BN_ * H_);                 // 384*64 floats
    float* zyxs = ws + 4 * (BN_ * H_) + 384 * 64;      // 384*64 floats
    _Float16* W2F = (_Float16*)(ws + 5 * (BN_ * H_));  // 32 KiB, 16B-aligned

    proj_kernel<<<384 + 8, 256, 0, stream>>>(X, Y, Wxx1, bxx1, Wyx1, byx1,
                                             W2xx, W2yx,
                                             PAxx, PCxx, PAyx, PCyx, W2F);
    pair_mfma_kernel<<<768, 256, 0, stream>>>(PAxx, PCxx, PAyx, PCyx,
                                              (const f32x4*)W2F, zxxs, zyxs);
    head_kernel<<<B_, 256, 0, stream>>>(zxxs, zyxs, b2xx, b2yx,
                                        Wd1, bd1, Wd2, bd2, (float*)d_out);
}